// Round 3
// baseline (586.879 us; speedup 1.0000x reference)
//
#include <hip/hip_runtime.h>
#include <math.h>

// Shapes: B=32, L=2048, E=512, H=512, V=32000
// Dead code: softmax over singleton axis == 1.0 -> attn_weights == 1/2048 exactly
// -> x/emb/attn_W/attn_b never read; c = relu(mean_L(encoder_out)).
// Mandatory HBM ~410 MB -> ~66 us BW floor; harness fixed floor ~388 us (poison+restore).
// R4 lesson: grid.sync() costs ~85 us each on 8-XCD MI355X -> multi-kernel chain wins.
// R1 lesson: fat fused logits+GRU kernel unions VGPR pressure -> occupancy drop on the
// BW-bound out_W stream. Keep K4 lean.
// R2 lesson: inter-pod bench noise is +-20-35 us (fills alone wobble +-2% = +-10 us);
// R1/R2 "regressions" were not attributable to any diff. This round: R0 structure
// (known best sample) + only strictly-dominating deltas:
//   (1) K3 shuffle reduce 6->4 values (r,z need only pr+qr / pz+qz),
//   (2) K4 lane-0 expsum atomics into 256 bins (logits ~ +-6, no max-sub needed),
//   (3) K5 parallel 32-block tail replaces single-block 3-pass LSE (~ -6 us),
//   (4) bin zeroing rides as K2's 97th block.
//
// d_out layout (fp32): logp [0,32000) | h_new [32000,64768) | attn_weights [64768,130304)

#define NCH 64   // L-chunks for encoder reduction: 64*32 = 2048 blocks (8/CU queued)
#define NBIN 256 // expsum bins (1 KB; ~125 atomics/bin, distinct addrs -> parallel at L2)

// ---------------- K1: partial sums of encoder_out, 32 rows per block ----------------
__global__ __launch_bounds__(256) void k_enc_partial(const float* __restrict__ enc,
                                                     float* __restrict__ partial) {
  const int tid = threadIdx.x;            // one float4 lane-column of the 1024-float row
  const int ch  = blockIdx.x;             // 0..63
  const int b   = blockIdx.y;             // 0..31
  const float4* src = (const float4*)enc + ((size_t)b * 2048 + (size_t)ch * 32) * 256 + tid;
  float4 acc = make_float4(0.f, 0.f, 0.f, 0.f);
#pragma unroll 8
  for (int l = 0; l < 32; ++l) {
    float4 v = src[(size_t)l * 256];
    acc.x += v.x; acc.y += v.y; acc.z += v.z; acc.w += v.w;
  }
  ((float4*)partial)[((size_t)b * NCH + ch) * 256 + tid] = acc;
}

// ---------------- K2: c = relu(mean) (blocks 0..31) + attn fill (32..95) + bin zero (96) ----------------
__global__ __launch_bounds__(256) void k_c_fill(const float* __restrict__ partial,
                                                float* __restrict__ c,
                                                float* __restrict__ out,
                                                float* __restrict__ Sbins) {
  const int bid = blockIdx.x;
  if (bid < 32) {
    const int idx4 = bid * 256 + threadIdx.x;   // 0..8191 float4s of c
    const int b = idx4 >> 8, d4 = idx4 & 255;
    const float4* p4 = (const float4*)partial + (size_t)b * NCH * 256 + d4;
    float4 s = make_float4(0.f, 0.f, 0.f, 0.f);
#pragma unroll 8
    for (int ch = 0; ch < NCH; ++ch) {
      float4 v = p4[(size_t)ch * 256];
      s.x += v.x; s.y += v.y; s.z += v.z; s.w += v.w;
    }
    const float sc = 1.0f / 2048.0f;
    float4 r;
    r.x = s.x > 0.f ? s.x * sc : 0.f;
    r.y = s.y > 0.f ? s.y * sc : 0.f;
    r.z = s.z > 0.f ? s.z * sc : 0.f;
    r.w = s.w > 0.f ? s.w * sc : 0.f;
    ((float4*)c)[idx4] = r;
  } else if (bid < 96) {
    const int i4 = (bid - 32) * 256 + threadIdx.x;   // 0..16383
    const float w = 1.0f / 2048.0f;
    ((float4*)out)[16192 + i4] = make_float4(w, w, w, w);
  } else {
    Sbins[threadIdx.x] = 0.f;   // 256 threads zero 256 bins (runs before K4)
  }
}

// ---------------- K3: bi-GRU cells, one wave per (dir, k), full batch ----------------
__global__ __launch_bounds__(256) void k_gru(
    const float* __restrict__ c, const float* __restrict__ h,
    const float* __restrict__ Wih_f, const float* __restrict__ Whh_f,
    const float* __restrict__ bih_f, const float* __restrict__ bhh_f,
    const float* __restrict__ Wih_b, const float* __restrict__ Whh_b,
    const float* __restrict__ bih_b, const float* __restrict__ bhh_b,
    float* __restrict__ out) {
  const int lane = threadIdx.x & 63;
  const int wid  = (blockIdx.x * 256 + threadIdx.x) >> 6;  // 0..1023
  const int dir  = wid >> 9;
  const int k    = wid & 511;
  const float* Wih = dir ? Wih_b : Wih_f;
  const float* Whh = dir ? Whh_b : Whh_f;
  const float* bih = dir ? bih_b : bih_f;
  const float* bhh = dir ? bhh_b : bhh_f;
  const float4* Wih4 = (const float4*)Wih;
  const float4* Whh4 = (const float4*)Whh;

  float4 wr[4], wz[4], wn[4];
#pragma unroll
  for (int i = 0; i < 4; ++i) {
    wr[i] = Wih4[(size_t)k * 256 + i * 64 + lane];
    wz[i] = Wih4[(size_t)(k + 512) * 256 + i * 64 + lane];
    wn[i] = Wih4[(size_t)(k + 1024) * 256 + i * 64 + lane];
  }
  float4 ur[2], uz[2], un[2];
#pragma unroll
  for (int i = 0; i < 2; ++i) {
    ur[i] = Whh4[(size_t)k * 128 + i * 64 + lane];
    uz[i] = Whh4[(size_t)(k + 512) * 128 + i * 64 + lane];
    un[i] = Whh4[(size_t)(k + 1024) * 128 + i * 64 + lane];
  }
  const float bkr = bih[k], bkz = bih[k + 512], bkn = bih[k + 1024];
  const float ckr = bhh[k], ckz = bhh[k + 512], ckn = bhh[k + 1024];

  const float4* c4 = (const float4*)c;
  const float4* h4 = (const float4*)h + (size_t)dir * 32 * 128;

  for (int b = 0; b < 32; ++b) {
    float pr = 0.f, pz = 0.f, pn = 0.f;
#pragma unroll
    for (int i = 0; i < 4; ++i) {
      float4 v = c4[b * 256 + i * 64 + lane];
      pr += v.x * wr[i].x + v.y * wr[i].y + v.z * wr[i].z + v.w * wr[i].w;
      pz += v.x * wz[i].x + v.y * wz[i].y + v.z * wz[i].z + v.w * wz[i].w;
      pn += v.x * wn[i].x + v.y * wn[i].y + v.z * wn[i].z + v.w * wn[i].w;
    }
    float qn = 0.f;
    {
      float qr = 0.f, qz = 0.f;
#pragma unroll
      for (int i = 0; i < 2; ++i) {
        float4 v = h4[b * 128 + i * 64 + lane];
        qr += v.x * ur[i].x + v.y * ur[i].y + v.z * ur[i].z + v.w * ur[i].w;
        qz += v.x * uz[i].x + v.y * uz[i].y + v.z * uz[i].z + v.w * uz[i].w;
        qn += v.x * un[i].x + v.y * un[i].y + v.z * un[i].z + v.w * un[i].w;
      }
      pr += qr;  // r,z gates only need the SUM of input/hidden partials
      pz += qz;  // -> 4 reduced values instead of 6 (24 shuffles/b, was 36)
    }
#pragma unroll
    for (int off = 32; off; off >>= 1) {
      pr += __shfl_xor(pr, off, 64);
      pz += __shfl_xor(pz, off, 64);
      pn += __shfl_xor(pn, off, 64);
      qn += __shfl_xor(qn, off, 64);
    }
    if (lane == 0) {
      float r = 1.f / (1.f + expf(-(pr + bkr + ckr)));
      float z = 1.f / (1.f + expf(-(pz + bkz + ckz)));
      float n = tanhf(pn + bkn + r * (qn + ckn));
      float hp = h[(size_t)dir * 32 * 512 + (size_t)b * 512 + k];
      out[32000 + dir * 16384 + b * 512 + k] = (1.f - z) * n + z * hp;
    }
  }
}

// ---------------- K4: logits[v] = dot(c_out[31], out_W[v]) + out_b[v]; expsum into bins ----------------
// Lean on purpose (R1 lesson): no LDS, no __syncthreads, lane0-only exp + fire-and-forget atomic.
__global__ __launch_bounds__(256) void k_logits(const float* __restrict__ outW,
                                                const float* __restrict__ outb,
                                                const float* __restrict__ dout,
                                                float* __restrict__ logits,
                                                float* __restrict__ Sbins) {
  const int lane = threadIdx.x & 63;
  const int v = (blockIdx.x * 256 + threadIdx.x) >> 6;  // 0..31999
  const float4* hf = (const float4*)(dout + 32000 + 31 * 512);
  const float4* hb = (const float4*)(dout + 32000 + 16384 + 31 * 512);
  const float4* W4 = (const float4*)outW + (size_t)v * 256;
  float p = 0.f;
#pragma unroll
  for (int i = 0; i < 4; ++i) {
    const int pos = i * 64 + lane;
    float4 cv = (pos < 128) ? hf[pos] : hb[pos - 128];
    float4 wv = W4[pos];
    p += cv.x * wv.x + cv.y * wv.y + cv.z * wv.z + cv.w * wv.w;
  }
#pragma unroll
  for (int off = 32; off; off >>= 1) p += __shfl_xor(p, off, 64);
  if (lane == 0) {
    const float l = p + outb[v];
    logits[v] = l;
    atomicAdd(&Sbins[v & (NBIN - 1)], expf(l));  // logits ~ +-6; no max-sub needed in fp32
  }
}

// ---------------- K5: tail — ls = log(sum bins); logp = logits - ls (32 blocks) ----------------
__global__ __launch_bounds__(256) void k5_tail(const float* __restrict__ logits,
                                               const float* __restrict__ Sbins,
                                               float* __restrict__ out) {
  __shared__ float red[4];
  __shared__ float s_ls;
  const int tid = threadIdx.x, lane = tid & 63, w = tid >> 6;
  float s = Sbins[tid];
#pragma unroll
  for (int off = 32; off; off >>= 1) s += __shfl_xor(s, off, 64);
  if (lane == 0) red[w] = s;
  __syncthreads();
  if (tid == 0) s_ls = logf(red[0] + red[1] + red[2] + red[3]);
  __syncthreads();
  const float ls = s_ls;
  if (tid < 250) {
    const int i4 = blockIdx.x * 250 + tid;   // 32 blocks * 250 = 8000 float4
    float4 v = ((const float4*)logits)[i4];
    ((float4*)out)[i4] = make_float4(v.x - ls, v.y - ls, v.z - ls, v.w - ls);
  }
}

extern "C" void kernel_launch(void* const* d_in, const int* in_sizes, int n_in,
                              void* d_out, int out_size, void* d_ws, size_t ws_size,
                              hipStream_t stream) {
  // 0:x 1:h 2:encoder_out 3:emb 4:attn_W 5:attn_b 6:W_ih_f 7:W_hh_f 8:b_ih_f 9:b_hh_f
  // 10:W_ih_b 11:W_hh_b 12:b_ih_b 13:b_hh_b 14:out_W 15:out_b
  const float* h     = (const float*)d_in[1];
  const float* enc   = (const float*)d_in[2];
  const float* Wih_f = (const float*)d_in[6];
  const float* Whh_f = (const float*)d_in[7];
  const float* bih_f = (const float*)d_in[8];
  const float* bhh_f = (const float*)d_in[9];
  const float* Wih_b = (const float*)d_in[10];
  const float* Whh_b = (const float*)d_in[11];
  const float* bih_b = (const float*)d_in[12];
  const float* bhh_b = (const float*)d_in[13];
  const float* outW  = (const float*)d_in[14];
  const float* outb  = (const float*)d_in[15];
  float* out = (float*)d_out;
  float* ws  = (float*)d_ws;

  float* partial = ws;                          // 32*NCH*1024 floats (8 MB)
  float* cbuf    = partial + 32 * NCH * 1024;   // 32768 floats
  float* logits  = cbuf + 32768;                // 32000 floats
  float* Sbins   = logits + 32000;              // 256 floats

  dim3 g1(NCH, 32);
  k_enc_partial<<<g1, 256, 0, stream>>>(enc, partial);
  k_c_fill<<<97, 256, 0, stream>>>(partial, cbuf, out, Sbins);
  k_gru<<<256, 256, 0, stream>>>(cbuf, h, Wih_f, Whh_f, bih_f, bhh_f,
                                 Wih_b, Whh_b, bih_b, bhh_b, out);
  k_logits<<<8000, 256, 0, stream>>>(outW, outb, out, logits, Sbins);
  k5_tail<<<32, 256, 0, stream>>>(logits, Sbins, out);
}

// Round 5
// 566.128 us; speedup vs baseline: 1.0367x; 1.0367x over previous
//
#include <hip/hip_runtime.h>
#include <math.h>

// Shapes: B=32, L=2048, E=512, H=512, V=32000
// Dead code: softmax over singleton axis == 1.0 -> attn_weights == 1/2048 exactly
// -> x/emb/attn_W/attn_b never read; c = relu(mean_L(encoder_out)).
// Mandatory HBM ~420 MB -> ~66 us BW floor; harness fixed floor ~388 us (poison+restore).
// Earlier lesson: grid.sync() costs ~85 us each on 8-XCD MI355X -> multi-kernel chain wins.
// R1 lesson: fat fused logits+GRU kernel unions VGPR pressure -> occupancy drop on the
// BW-bound out_W stream. Keep K4 lean.
// R1-R3 lesson (561/578/587 vs 542.8 baseline, 3/3 regressions): the K4 expsum
// atomicAdd into 256 bins = 16 cache lines; 2000 device-scope same-line atomics/line
// serialize at the coherence point (8 non-coherent XCD L2s) -> 20-50 us drain that K4
// must retire before completing. NO GLOBAL ATOMICS anywhere in this chain.
// K5 instead parallelizes LSE by REDUNDANCY: 32 blocks each recompute the full expsum
// from L2-hot logits (128 KB/block), then write their own slice. No cross-block comms.
// R4: container acquisition failed twice (infra) — identical kernel resubmitted.
//
// d_out layout (fp32): logp [0,32000) | h_new [32000,64768) | attn_weights [64768,130304)

#define NCH 64  // L-chunks for encoder reduction: 64*32 = 2048 blocks (8/CU queued)

// ---------------- K1: partial sums of encoder_out, 32 rows per block ----------------
__global__ __launch_bounds__(256) void k_enc_partial(const float* __restrict__ enc,
                                                     float* __restrict__ partial) {
  const int tid = threadIdx.x;            // one float4 lane-column of the 1024-float row
  const int ch  = blockIdx.x;             // 0..63
  const int b   = blockIdx.y;             // 0..31
  const float4* src = (const float4*)enc + ((size_t)b * 2048 + (size_t)ch * 32) * 256 + tid;
  float4 acc = make_float4(0.f, 0.f, 0.f, 0.f);
#pragma unroll 8
  for (int l = 0; l < 32; ++l) {
    float4 v = src[(size_t)l * 256];
    acc.x += v.x; acc.y += v.y; acc.z += v.z; acc.w += v.w;
  }
  ((float4*)partial)[((size_t)b * NCH + ch) * 256 + tid] = acc;
}

// ---------------- K2: c = relu(mean) (blocks 0..31, float4) + attn fill (blocks 32..95) ----------------
__global__ __launch_bounds__(256) void k_c_fill(const float* __restrict__ partial,
                                                float* __restrict__ c,
                                                float* __restrict__ out) {
  const int bid = blockIdx.x;
  if (bid < 32) {
    const int idx4 = bid * 256 + threadIdx.x;   // 0..8191 float4s of c
    const int b = idx4 >> 8, d4 = idx4 & 255;
    const float4* p4 = (const float4*)partial + (size_t)b * NCH * 256 + d4;
    float4 s = make_float4(0.f, 0.f, 0.f, 0.f);
#pragma unroll 8
    for (int ch = 0; ch < NCH; ++ch) {
      float4 v = p4[(size_t)ch * 256];
      s.x += v.x; s.y += v.y; s.z += v.z; s.w += v.w;
    }
    const float sc = 1.0f / 2048.0f;
    float4 r;
    r.x = s.x > 0.f ? s.x * sc : 0.f;
    r.y = s.y > 0.f ? s.y * sc : 0.f;
    r.z = s.z > 0.f ? s.z * sc : 0.f;
    r.w = s.w > 0.f ? s.w * sc : 0.f;
    ((float4*)c)[idx4] = r;
  } else {
    const int i4 = (bid - 32) * 256 + threadIdx.x;   // 0..16383
    const float w = 1.0f / 2048.0f;
    ((float4*)out)[16192 + i4] = make_float4(w, w, w, w);
  }
}

// ---------------- K3: bi-GRU cells, one wave per (dir, k), full batch ----------------
__global__ __launch_bounds__(256) void k_gru(
    const float* __restrict__ c, const float* __restrict__ h,
    const float* __restrict__ Wih_f, const float* __restrict__ Whh_f,
    const float* __restrict__ bih_f, const float* __restrict__ bhh_f,
    const float* __restrict__ Wih_b, const float* __restrict__ Whh_b,
    const float* __restrict__ bih_b, const float* __restrict__ bhh_b,
    float* __restrict__ out) {
  const int lane = threadIdx.x & 63;
  const int wid  = (blockIdx.x * 256 + threadIdx.x) >> 6;  // 0..1023
  const int dir  = wid >> 9;
  const int k    = wid & 511;
  const float* Wih = dir ? Wih_b : Wih_f;
  const float* Whh = dir ? Whh_b : Whh_f;
  const float* bih = dir ? bih_b : bih_f;
  const float* bhh = dir ? bhh_b : bhh_f;
  const float4* Wih4 = (const float4*)Wih;
  const float4* Whh4 = (const float4*)Whh;

  float4 wr[4], wz[4], wn[4];
#pragma unroll
  for (int i = 0; i < 4; ++i) {
    wr[i] = Wih4[(size_t)k * 256 + i * 64 + lane];
    wz[i] = Wih4[(size_t)(k + 512) * 256 + i * 64 + lane];
    wn[i] = Wih4[(size_t)(k + 1024) * 256 + i * 64 + lane];
  }
  float4 ur[2], uz[2], un[2];
#pragma unroll
  for (int i = 0; i < 2; ++i) {
    ur[i] = Whh4[(size_t)k * 128 + i * 64 + lane];
    uz[i] = Whh4[(size_t)(k + 512) * 128 + i * 64 + lane];
    un[i] = Whh4[(size_t)(k + 1024) * 128 + i * 64 + lane];
  }
  const float bkr = bih[k], bkz = bih[k + 512], bkn = bih[k + 1024];
  const float ckr = bhh[k], ckz = bhh[k + 512], ckn = bhh[k + 1024];

  const float4* c4 = (const float4*)c;
  const float4* h4 = (const float4*)h + (size_t)dir * 32 * 128;

  for (int b = 0; b < 32; ++b) {
    float pr = 0.f, pz = 0.f, pn = 0.f;
#pragma unroll
    for (int i = 0; i < 4; ++i) {
      float4 v = c4[b * 256 + i * 64 + lane];
      pr += v.x * wr[i].x + v.y * wr[i].y + v.z * wr[i].z + v.w * wr[i].w;
      pz += v.x * wz[i].x + v.y * wz[i].y + v.z * wz[i].z + v.w * wz[i].w;
      pn += v.x * wn[i].x + v.y * wn[i].y + v.z * wn[i].z + v.w * wn[i].w;
    }
    float qn = 0.f;
    {
      float qr = 0.f, qz = 0.f;
#pragma unroll
      for (int i = 0; i < 2; ++i) {
        float4 v = h4[b * 128 + i * 64 + lane];
        qr += v.x * ur[i].x + v.y * ur[i].y + v.z * ur[i].z + v.w * ur[i].w;
        qz += v.x * uz[i].x + v.y * uz[i].y + v.z * uz[i].z + v.w * uz[i].w;
        qn += v.x * un[i].x + v.y * un[i].y + v.z * un[i].z + v.w * un[i].w;
      }
      pr += qr;  // r,z gates only need the SUM of input/hidden partials
      pz += qz;  // -> 4 reduced values instead of 6 (24 shuffles/b, was 36)
    }
#pragma unroll
    for (int off = 32; off; off >>= 1) {
      pr += __shfl_xor(pr, off, 64);
      pz += __shfl_xor(pz, off, 64);
      pn += __shfl_xor(pn, off, 64);
      qn += __shfl_xor(qn, off, 64);
    }
    if (lane == 0) {
      float r = 1.f / (1.f + expf(-(pr + bkr + ckr)));
      float z = 1.f / (1.f + expf(-(pz + bkz + ckz)));
      float n = tanhf(pn + bkn + r * (qn + ckn));
      float hp = h[(size_t)dir * 32 * 512 + (size_t)b * 512 + k];
      out[32000 + dir * 16384 + b * 512 + k] = (1.f - z) * n + z * hp;
    }
  }
}

// ---------------- K4: logits[v] = dot(c_out[31], out_W[v]) + out_b[v] (lean, pure stores) ----------------
__global__ __launch_bounds__(256) void k_logits(const float* __restrict__ outW,
                                                const float* __restrict__ outb,
                                                const float* __restrict__ dout,
                                                float* __restrict__ logits) {
  const int lane = threadIdx.x & 63;
  const int v = (blockIdx.x * 256 + threadIdx.x) >> 6;  // 0..31999
  const float4* hf = (const float4*)(dout + 32000 + 31 * 512);
  const float4* hb = (const float4*)(dout + 32000 + 16384 + 31 * 512);
  const float4* W4 = (const float4*)outW + (size_t)v * 256;
  float p = 0.f;
#pragma unroll
  for (int i = 0; i < 4; ++i) {
    const int pos = i * 64 + lane;
    float4 cv = (pos < 128) ? hf[pos] : hb[pos - 128];
    float4 wv = W4[pos];
    p += cv.x * wv.x + cv.y * wv.y + cv.z * wv.z + cv.w * wv.w;
  }
#pragma unroll
  for (int off = 32; off; off >>= 1) p += __shfl_xor(p, off, 64);
  if (lane == 0) logits[v] = p + outb[v];
}

// ---------------- K5: parallel LSE by redundancy — 32 blocks, each recomputes expsum ----------------
// logits ~ +-6 (0.05-scale weights) -> exp without max-subtraction is safe in fp32.
// Each block streams all 8000 float4s (L2-hot), reduces, then writes its own slice.
__global__ __launch_bounds__(256) void k5_logp(const float* __restrict__ logits,
                                               float* __restrict__ out) {
  __shared__ float red[4];
  __shared__ float s_ls;
  const int tid = threadIdx.x, lane = tid & 63, w = tid >> 6;
  const float4* l4 = (const float4*)logits;
  float s = 0.f;
  for (int i = tid; i < 8000; i += 256) {
    float4 v = l4[i];
    s += expf(v.x) + expf(v.y) + expf(v.z) + expf(v.w);
  }
#pragma unroll
  for (int off = 32; off; off >>= 1) s += __shfl_xor(s, off, 64);
  if (lane == 0) red[w] = s;
  __syncthreads();
  if (tid == 0) s_ls = logf(red[0] + red[1] + red[2] + red[3]);
  __syncthreads();
  const float ls = s_ls;
  if (tid < 250) {
    const int i4 = blockIdx.x * 250 + tid;   // 32 blocks * 250 = 8000 float4
    float4 v = l4[i4];
    ((float4*)out)[i4] = make_float4(v.x - ls, v.y - ls, v.z - ls, v.w - ls);
  }
}

extern "C" void kernel_launch(void* const* d_in, const int* in_sizes, int n_in,
                              void* d_out, int out_size, void* d_ws, size_t ws_size,
                              hipStream_t stream) {
  // 0:x 1:h 2:encoder_out 3:emb 4:attn_W 5:attn_b 6:W_ih_f 7:W_hh_f 8:b_ih_f 9:b_hh_f
  // 10:W_ih_b 11:W_hh_b 12:b_ih_b 13:b_hh_b 14:out_W 15:out_b
  const float* h     = (const float*)d_in[1];
  const float* enc   = (const float*)d_in[2];
  const float* Wih_f = (const float*)d_in[6];
  const float* Whh_f = (const float*)d_in[7];
  const float* bih_f = (const float*)d_in[8];
  const float* bhh_f = (const float*)d_in[9];
  const float* Wih_b = (const float*)d_in[10];
  const float* Whh_b = (const float*)d_in[11];
  const float* bih_b = (const float*)d_in[12];
  const float* bhh_b = (const float*)d_in[13];
  const float* outW  = (const float*)d_in[14];
  const float* outb  = (const float*)d_in[15];
  float* out = (float*)d_out;
  float* ws  = (float*)d_ws;

  float* partial = ws;                          // 32*NCH*1024 floats (8 MB)
  float* cbuf    = partial + 32 * NCH * 1024;   // 32768 floats
  float* logits  = cbuf + 32768;                // 32000 floats

  dim3 g1(NCH, 32);
  k_enc_partial<<<g1, 256, 0, stream>>>(enc, partial);
  k_c_fill<<<96, 256, 0, stream>>>(partial, cbuf, out);
  k_gru<<<256, 256, 0, stream>>>(cbuf, h, Wih_f, Whh_f, bih_f, bhh_f,
                                 Wih_b, Whh_b, bih_b, bhh_b, out);
  k_logits<<<8000, 256, 0, stream>>>(outW, outb, out, logits);
  k5_logp<<<32, 256, 0, stream>>>(logits, out);
}